// Round 2
// baseline (1529.451 us; speedup 1.0000x reference)
//
#include <hip/hip_runtime.h>
#include <hip/hip_bf16.h>
#include <stdint.h>

#define NGRAPH 64
#define NNODE  2048
#define NT     (NGRAPH * NNODE)   // 131072
#define DIN    512
#define DHID   256
#define DOUT   256
#define KKEEP  410
#define NEG_SLOPE 0.2f

// ---------------------------------------------------------------------------
// fp32 tiled GEMM: C[M,N] = A[M,K] @ B[K,N], all row-major.
// BM=BN=128, BK=16, 256 threads, 8x8 micro-tile per thread.
// M % 128 == 0, N % 128 == 0, K % 16 == 0 (true for both GEMMs here).
// ---------------------------------------------------------------------------
#define BM 128
#define BN 128
#define BK 16

__global__ __launch_bounds__(256)
void gemm_f32(const float* __restrict__ A, const float* __restrict__ Bm,
              float* __restrict__ C, int M, int N, int Kd) {
    __shared__ float As[BK][BM + 4];
    __shared__ float Bs[BK][BN + 4];
    const int tid = threadIdx.x;
    const int r0 = blockIdx.y * BM;
    const int c0 = blockIdx.x * BN;
    const int tx = tid & 15;
    const int ty = tid >> 4;

    float acc[8][8];
#pragma unroll
    for (int i = 0; i < 8; i++)
#pragma unroll
        for (int j = 0; j < 8; j++) acc[i][j] = 0.f;

    for (int k0 = 0; k0 < Kd; k0 += BK) {
        // Load A tile (128 rows x 16 k) as 512 float4, 2 per thread, transpose to As[k][row]
#pragma unroll
        for (int l = 0; l < 2; l++) {
            int flat = tid + l * 256;          // [0,512)
            int kq = flat & 3;                 // float4 index along k
            int row = flat >> 2;               // [0,128)
            const float4 a4 = *reinterpret_cast<const float4*>(
                &A[(size_t)(r0 + row) * Kd + k0 + kq * 4]);
            As[kq * 4 + 0][row] = a4.x;
            As[kq * 4 + 1][row] = a4.y;
            As[kq * 4 + 2][row] = a4.z;
            As[kq * 4 + 3][row] = a4.w;
        }
        // Load B tile (16 k x 128 cols) as 512 float4, 2 per thread
#pragma unroll
        for (int l = 0; l < 2; l++) {
            int flat = tid + l * 256;
            int cq = flat & 31;                // [0,32) float4 along col
            int k  = flat >> 5;                // [0,16)
            *reinterpret_cast<float4*>(&Bs[k][cq * 4]) =
                *reinterpret_cast<const float4*>(
                    &Bm[(size_t)(k0 + k) * N + c0 + cq * 4]);
        }
        __syncthreads();

#pragma unroll
        for (int k = 0; k < BK; k++) {
            float a[8], b[8];
#pragma unroll
            for (int u = 0; u < 8; u++) a[u] = As[k][ty * 8 + u];
#pragma unroll
            for (int u = 0; u < 8; u++) b[u] = Bs[k][tx * 8 + u];
#pragma unroll
            for (int i = 0; i < 8; i++)
#pragma unroll
                for (int j = 0; j < 8; j++)
                    acc[i][j] = fmaf(a[i], b[j], acc[i][j]);
        }
        __syncthreads();
    }

#pragma unroll
    for (int i = 0; i < 8; i++) {
        float4 v0 = {acc[i][0], acc[i][1], acc[i][2], acc[i][3]};
        float4 v1 = {acc[i][4], acc[i][5], acc[i][6], acc[i][7]};
        size_t off = (size_t)(r0 + ty * 8 + i) * N + c0 + tx * 8;
        *reinterpret_cast<float4*>(&C[off])     = v0;
        *reinterpret_cast<float4*>(&C[off + 4]) = v1;
    }
}

// ---------------------------------------------------------------------------
// Per-node attention dot products: a_out[v] = {a_src_h0, a_src_h1, a_dst_h0, a_dst_h1}
// xp is [NT, 512] (head0 cols 0..255, head1 cols 256..511).
// One wave (64 lanes) per node; lane handles 4 channels per head.
// ---------------------------------------------------------------------------
__global__ __launch_bounds__(256)
void att_dots(const float* __restrict__ xp, const float* __restrict__ att_src,
              const float* __restrict__ att_dst, float* __restrict__ a_out) {
    const int v = blockIdx.x * 4 + (threadIdx.x >> 6);
    const int lane = threadIdx.x & 63;
    const float4 x0 = *reinterpret_cast<const float4*>(&xp[(size_t)v * 512 + lane * 4]);
    const float4 x1 = *reinterpret_cast<const float4*>(&xp[(size_t)v * 512 + 256 + lane * 4]);
    const float4 s0 = *reinterpret_cast<const float4*>(&att_src[lane * 4]);
    const float4 s1 = *reinterpret_cast<const float4*>(&att_src[256 + lane * 4]);
    const float4 d0 = *reinterpret_cast<const float4*>(&att_dst[lane * 4]);
    const float4 d1 = *reinterpret_cast<const float4*>(&att_dst[256 + lane * 4]);

    float vs0 = x0.x * s0.x + x0.y * s0.y + x0.z * s0.z + x0.w * s0.w;
    float vs1 = x1.x * s1.x + x1.y * s1.y + x1.z * s1.z + x1.w * s1.w;
    float vd0 = x0.x * d0.x + x0.y * d0.y + x0.z * d0.z + x0.w * d0.w;
    float vd1 = x1.x * d1.x + x1.y * d1.y + x1.z * d1.z + x1.w * d1.w;

#pragma unroll
    for (int off = 32; off; off >>= 1) {
        vs0 += __shfl_xor(vs0, off);
        vs1 += __shfl_xor(vs1, off);
        vd0 += __shfl_xor(vd0, off);
        vd1 += __shfl_xor(vd1, off);
    }
    if (lane == 0) {
        float4 o = {vs0, vs1, vd0, vd1};
        *reinterpret_cast<float4*>(&a_out[(size_t)v * 4]) = o;
    }
}

__device__ __forceinline__ float leaky(float x) {
    return x >= 0.f ? x : NEG_SLOPE * x;
}

// ---------------------------------------------------------------------------
// Attention combine (chain graph): out[v] = mean_h( alpha_in*xp[v-1] + alpha_self*xp[v] ) + bias
// optional ReLU. One wave per node, lane covers 4 channels (of 256).
// ---------------------------------------------------------------------------
__global__ __launch_bounds__(256)
void att_combine(const float* __restrict__ xp, const float* __restrict__ a,
                 const float* __restrict__ bias, float* __restrict__ hout,
                 int do_relu) {
    const int v = blockIdx.x * 4 + (threadIdx.x >> 6);
    const int lane = threadIdx.x & 63;
    const int j = v & (NNODE - 1);

    const float4 av = *reinterpret_cast<const float4*>(&a[(size_t)v * 4]); // {s0,s1,d0,d1}

    float ain0 = 0.f, ain1 = 0.f, asf0 = 1.f, asf1 = 1.f;
    float4 xprev0 = {0.f, 0.f, 0.f, 0.f}, xprev1 = {0.f, 0.f, 0.f, 0.f};
    if (j > 0) {
        const float4 ap = *reinterpret_cast<const float4*>(&a[(size_t)(v - 1) * 4]);
        // head 0
        {
            float ein = leaky(ap.x + av.z);
            float esf = leaky(av.x + av.z);
            float m = fmaxf(ein, esf);
            float win = expf(ein - m);
            float wsf = expf(esf - m);
            float den = win + wsf + 1e-16f;
            ain0 = win / den;
            asf0 = wsf / den;
        }
        // head 1
        {
            float ein = leaky(ap.y + av.w);
            float esf = leaky(av.y + av.w);
            float m = fmaxf(ein, esf);
            float win = expf(ein - m);
            float wsf = expf(esf - m);
            float den = win + wsf + 1e-16f;
            ain1 = win / den;
            asf1 = wsf / den;
        }
        xprev0 = *reinterpret_cast<const float4*>(&xp[(size_t)(v - 1) * 512 + lane * 4]);
        xprev1 = *reinterpret_cast<const float4*>(&xp[(size_t)(v - 1) * 512 + 256 + lane * 4]);
    }

    const float4 xv0 = *reinterpret_cast<const float4*>(&xp[(size_t)v * 512 + lane * 4]);
    const float4 xv1 = *reinterpret_cast<const float4*>(&xp[(size_t)v * 512 + 256 + lane * 4]);
    const float4 bb  = *reinterpret_cast<const float4*>(&bias[lane * 4]);

    float4 r;
    r.x = 0.5f * (ain0 * xprev0.x + asf0 * xv0.x + ain1 * xprev1.x + asf1 * xv1.x) + bb.x;
    r.y = 0.5f * (ain0 * xprev0.y + asf0 * xv0.y + ain1 * xprev1.y + asf1 * xv1.y) + bb.y;
    r.z = 0.5f * (ain0 * xprev0.z + asf0 * xv0.z + ain1 * xprev1.z + asf1 * xv1.z) + bb.z;
    r.w = 0.5f * (ain0 * xprev0.w + asf0 * xv0.w + ain1 * xprev1.w + asf1 * xv1.w) + bb.w;
    if (do_relu) {
        r.x = fmaxf(r.x, 0.f); r.y = fmaxf(r.y, 0.f);
        r.z = fmaxf(r.z, 0.f); r.w = fmaxf(r.w, 0.f);
    }
    *reinterpret_cast<float4*>(&hout[(size_t)v * 256 + lane * 4]) = r;
}

// ---------------------------------------------------------------------------
// SAGPool score: score[v] = h[v].pW_root + (j>0 ? h[v-1].pW_rel : 0) + pb
// One wave per node.
// ---------------------------------------------------------------------------
__global__ __launch_bounds__(256)
void score_kernel(const float* __restrict__ h, const float* __restrict__ pW_root,
                  const float* __restrict__ pW_rel, const float* __restrict__ pb,
                  float* __restrict__ score) {
    const int v = blockIdx.x * 4 + (threadIdx.x >> 6);
    const int lane = threadIdx.x & 63;
    const int j = v & (NNODE - 1);

    const float4 hv = *reinterpret_cast<const float4*>(&h[(size_t)v * 256 + lane * 4]);
    const float4 wr = *reinterpret_cast<const float4*>(&pW_root[lane * 4]);
    float s = hv.x * wr.x + hv.y * wr.y + hv.z * wr.z + hv.w * wr.w;
    if (j > 0) {
        const float4 hp = *reinterpret_cast<const float4*>(&h[(size_t)(v - 1) * 256 + lane * 4]);
        const float4 wl = *reinterpret_cast<const float4*>(&pW_rel[lane * 4]);
        s += hp.x * wl.x + hp.y * wl.y + hp.z * wl.z + hp.w * wl.w;
    }
#pragma unroll
    for (int off = 32; off; off >>= 1) s += __shfl_xor(s, off);
    if (lane == 0) score[v] = s + pb[0];
}

// ---------------------------------------------------------------------------
// Per-graph top-K (bitonic sort of 2048 keys), gated mean pool, classifier.
// One block (1024 threads) per graph.
// Key = (~ordered(score) << 32) | index  -> ascending sort = score desc, index asc
// (matches jax.lax.top_k tie-breaking).
// ---------------------------------------------------------------------------
__global__ __launch_bounds__(1024)
void topk_pool(const float* __restrict__ score, const float* __restrict__ h,
               const float* __restrict__ cls_W, const float* __restrict__ cls_b,
               float* __restrict__ out) {
    __shared__ unsigned long long keys[NNODE];
    __shared__ float sc[NNODE];
    __shared__ float partial[4][256];
    __shared__ float red[8];

    const int b = blockIdx.x;
    const int tid = threadIdx.x;

    for (int i = tid; i < NNODE; i += 1024) {
        float v = score[(size_t)b * NNODE + i];
        sc[i] = v;
        unsigned u = __float_as_uint(v);
        u = (u & 0x80000000u) ? ~u : (u | 0x80000000u);  // order-preserving map
        keys[i] = ((unsigned long long)(~u) << 32) | (unsigned)i;
    }
    __syncthreads();

    // bitonic sort ascending
    for (int k = 2; k <= NNODE; k <<= 1) {
        for (int jj = k >> 1; jj > 0; jj >>= 1) {
            int i = ((tid & ~(jj - 1)) << 1) | (tid & (jj - 1));
            int ixj = i | jj;
            unsigned long long a = keys[i], c = keys[ixj];
            bool up = ((i & k) == 0);
            if ((a > c) == up) { keys[i] = c; keys[ixj] = a; }
            __syncthreads();
        }
    }

    // gated pooling over top-K
    const int g = tid >> 8;      // [0,4)
    const int c = tid & 255;     // channel
    float acc = 0.f;
    for (int kk = g; kk < KKEEP; kk += 4) {
        int idx = (int)(keys[kk] & 0xffffffffu);
        float gate = tanhf(sc[idx]);
        acc += h[((size_t)b * NNODE + idx) * 256 + c] * gate;
    }
    partial[g][c] = acc;
    __syncthreads();

    if (tid < 256) {
        float pooled = (partial[0][tid] + partial[1][tid] +
                        partial[2][tid] + partial[3][tid]) / (float)KKEEP;
        float p0 = pooled * cls_W[tid * 2 + 0];
        float p1 = pooled * cls_W[tid * 2 + 1];
#pragma unroll
        for (int off = 32; off; off >>= 1) {
            p0 += __shfl_down(p0, off);
            p1 += __shfl_down(p1, off);
        }
        if ((tid & 63) == 0) {
            red[(tid >> 6) * 2 + 0] = p0;
            red[(tid >> 6) * 2 + 1] = p1;
        }
    }
    __syncthreads();
    if (tid == 0) {
        out[b * 2 + 0] = red[0] + red[2] + red[4] + red[6] + cls_b[0];
        out[b * 2 + 1] = red[1] + red[3] + red[5] + red[7] + cls_b[1];
    }
}

// ---------------------------------------------------------------------------

extern "C" void kernel_launch(void* const* d_in, const int* in_sizes, int n_in,
                              void* d_out, int out_size, void* d_ws, size_t ws_size,
                              hipStream_t stream) {
    const float* x        = (const float*)d_in[0];
    const float* W1       = (const float*)d_in[1];
    const float* att_src1 = (const float*)d_in[2];
    const float* att_dst1 = (const float*)d_in[3];
    const float* b1       = (const float*)d_in[4];
    const float* W2       = (const float*)d_in[5];
    const float* att_src2 = (const float*)d_in[6];
    const float* att_dst2 = (const float*)d_in[7];
    const float* b2       = (const float*)d_in[8];
    const float* pW_root  = (const float*)d_in[9];
    const float* pW_rel   = (const float*)d_in[10];
    const float* pb       = (const float*)d_in[11];
    const float* cls_W    = (const float*)d_in[12];
    const float* cls_b    = (const float*)d_in[13];
    float* out = (float*)d_out;

    // workspace layout (fp32):
    //   xp     : NT*512   (shared by layer1 and layer2 projections)
    //   hbuf   : NT*256   (h1, later reused as h2)
    //   adots  : NT*4
    //   scores : NT
    float* xp     = (float*)d_ws;
    float* hbuf   = xp + (size_t)NT * 512;
    float* adots  = hbuf + (size_t)NT * 256;
    float* scores = adots + (size_t)NT * 4;

    // N for BOTH gemms is HEADS*D_HID = HEADS*D_OUT = 512 -> grid.x = 512/BN = 4
    // (round-1 bug: DIN*2/BN = 8 launched phantom blocks that overwrote xp rows)
    const dim3 gemm_grid(512 / BN, NT / BM);
    const int nwave_blocks = NT / 4;   // 32768

    // ---- layer 1: xp1 = x @ W1 ; dots ; combine(+bias,+relu) -> h1
    gemm_f32<<<gemm_grid, 256, 0, stream>>>(x, W1, xp, NT, 512, DIN);
    att_dots<<<nwave_blocks, 256, 0, stream>>>(xp, att_src1, att_dst1, adots);
    att_combine<<<nwave_blocks, 256, 0, stream>>>(xp, adots, b1, hbuf, 1);

    // ---- layer 2: xp2 = h1 @ W2 ; dots ; combine(+bias) -> h2 (reuse hbuf)
    gemm_f32<<<gemm_grid, 256, 0, stream>>>(hbuf, W2, xp, NT, 512, DHID);
    att_dots<<<nwave_blocks, 256, 0, stream>>>(xp, att_src2, att_dst2, adots);
    att_combine<<<nwave_blocks, 256, 0, stream>>>(xp, adots, b2, hbuf, 0);

    // ---- SAGPool score, top-k gated mean pool, classifier
    score_kernel<<<nwave_blocks, 256, 0, stream>>>(hbuf, pW_root, pW_rel, pb, scores);
    topk_pool<<<NGRAPH, 1024, 0, stream>>>(scores, hbuf, cls_W, cls_b, out);
}

// Round 3
// 639.996 us; speedup vs baseline: 2.3898x; 2.3898x over previous
//
#include <hip/hip_runtime.h>
#include <hip/hip_bf16.h>
#include <stdint.h>

#define NGRAPH 64
#define NNODE  2048
#define NT     (NGRAPH * NNODE)   // 131072
#define KKEEP  410
#define NEG_SLOPE 0.2f

typedef __attribute__((ext_vector_type(4))) float  f32x4;
typedef __attribute__((ext_vector_type(8))) short  short8v;
typedef __attribute__((ext_vector_type(8))) __bf16 bf16x8;

// ---------------------------------------------------------------------------
// MFMA 16x16x32 bf16 — SFINAE tag-dispatch over the builtin's operand type
// (some toolchains declare v8i16 operands, newer ones v8bf16).
// ---------------------------------------------------------------------------
template <typename A>
__device__ __forceinline__ auto mfma_call(A a, A b, f32x4 c, int)
    -> decltype(__builtin_amdgcn_mfma_f32_16x16x32_bf16(a, b, c, 0, 0, 0)) {
    return __builtin_amdgcn_mfma_f32_16x16x32_bf16(a, b, c, 0, 0, 0);
}
template <typename A>
__device__ __forceinline__ f32x4 mfma_call(A a, A b, f32x4 c, long) {
    return __builtin_amdgcn_mfma_f32_16x16x32_bf16(
        __builtin_bit_cast(bf16x8, a), __builtin_bit_cast(bf16x8, b), c, 0, 0, 0);
}
__device__ __forceinline__ f32x4 MFMA(short8v a, short8v b, f32x4 c) {
    return mfma_call(a, b, c, 0);
}

// split x = hi + lo (bf16 RNE; x-hi exact in fp32; bf16 exponent = f32 -> no denorm trap)
__device__ __forceinline__ void split_bf16(float x, short& hi, short& lo) {
    __bf16 h = (__bf16)x;
    float  hf = (float)h;
    __bf16 l = (__bf16)(x - hf);
    hi = __builtin_bit_cast(short, h);
    lo = __builtin_bit_cast(short, l);
}

__device__ __forceinline__ void gload16(const void* g, void* lds) {
    __builtin_amdgcn_global_load_lds(
        (const __attribute__((address_space(1))) void*)g,
        (__attribute__((address_space(3))) void*)lds,
        16, 0, 0);
}

// ---------------------------------------------------------------------------
// Split-bf16 MFMA GEMM:  C[M,512] = A[M,Kd](fp32) @ W[Kd,512]  via
//   C = Ah@Bh + Ah@Bl + Al@Bh   (fp32 MFMA accumulate)
// B is pre-split & pre-transposed: Bth/Btl are [512][Kd] bf16 (row = N col).
// Tile 128x128xBK32, 4 waves (2x2 of 64x64), 16x16x32 MFMA, 4x4 frags/wave.
// A: reg-staged fp32 -> split -> ds_write (in-loop conversion, no extra ws).
// B: global_load_lds width-16 (linear LDS; fragment reads are dense sweeps).
// ---------------------------------------------------------------------------
#define TBM 128
#define TBN 128
#define TBK 32

__global__ __launch_bounds__(256)
void gemm_split_bf16(const float* __restrict__ A,
                     const short* __restrict__ Bth,
                     const short* __restrict__ Btl,
                     float* __restrict__ C,
                     int Kd) {
    __shared__ short sAh[TBM * TBK];
    __shared__ short sAl[TBM * TBK];
    __shared__ short sBh[TBN * TBK];
    __shared__ short sBl[TBN * TBK];

    // XCD-aware bijective swizzle (gridDim.x = 4096, %8 == 0): each XCD gets a
    // contiguous wg chunk -> all 4 N-blocks of a row-stripe share one L2.
    const int cpx = gridDim.x >> 3;
    const int wg  = (blockIdx.x & 7) * cpx + (blockIdx.x >> 3);
    const int bx = wg & 3;          // N/128 = 4 column blocks
    const int by = wg >> 2;
    const int R0 = by * TBM;
    const int c0 = bx * TBN;

    const int tid  = threadIdx.x;
    const int lane = tid & 63;
    const int wid  = tid >> 6;
    const int wm = wid >> 1, wn = wid & 1;

    f32x4 acc[4][4];
#pragma unroll
    for (int i = 0; i < 4; i++)
#pragma unroll
        for (int j = 0; j < 4; j++) acc[i][j] = (f32x4)(0.0f);

    // A staging map: 128x32 fp32 tile = 1024 float4 chunks; thread t handles
    // chunks t + 256*i -> row = (t>>3)+32i, q = t&7 (8 float4 per row).
    const int ar = tid >> 3;
    const int aq = tid & 7;
    // B gload map: lane slot (per wave-issue) covers row wid*32+16i+(lane>>2),
    // chunk (lane&3)*8 elems; LDS dest = uniform base + lane*16 (HW rule).
    const int brow0 = wid * 32 + (lane >> 2);
    const int bke   = (lane & 3) * 8;

    const int fr = lane & 15, kg = lane >> 4;
    const int nk = Kd / TBK;

    for (int t = 0; t < nk; ++t) {
        // ---- B tiles: 2 issues per wave per tile (8KB each)
#pragma unroll
        for (int i = 0; i < 2; ++i) {
            const int r = brow0 + 16 * i;
            const size_t go = (size_t)(c0 + r) * Kd + t * TBK + bke;
            gload16(Bth + go, (char*)sBh + wid * 2048 + i * 1024);
            gload16(Btl + go, (char*)sBl + wid * 2048 + i * 1024);
        }
        // ---- A tile: 4x(float4 load -> split -> 2x ds_write_b64)
        {
            const float* abase = A + (size_t)(R0 + ar) * Kd + t * TBK + aq * 4;
#pragma unroll
            for (int i = 0; i < 4; ++i) {
                const float4 v = *reinterpret_cast<const float4*>(abase + (size_t)(32 * i) * Kd);
                short4 hh, ll;
                split_bf16(v.x, hh.x, ll.x);
                split_bf16(v.y, hh.y, ll.y);
                split_bf16(v.z, hh.z, ll.z);
                split_bf16(v.w, hh.w, ll.w);
                const int eb = (ar + 32 * i) * TBK + aq * 4;
                *reinterpret_cast<short4*>(&sAh[eb]) = hh;
                *reinterpret_cast<short4*>(&sAl[eb]) = ll;
            }
        }
        __syncthreads();   // drains vmcnt (gload_lds) + lgkmcnt (ds_write)

        short8v ah[4], al[4], bh[4], bl[4];
#pragma unroll
        for (int mi = 0; mi < 4; ++mi) {
            const int r = wm * 64 + mi * 16 + fr;
            ah[mi] = *reinterpret_cast<const short8v*>(&sAh[r * TBK + kg * 8]);
            al[mi] = *reinterpret_cast<const short8v*>(&sAl[r * TBK + kg * 8]);
        }
#pragma unroll
        for (int ni = 0; ni < 4; ++ni) {
            const int r = wn * 64 + ni * 16 + fr;
            bh[ni] = *reinterpret_cast<const short8v*>(&sBh[r * TBK + kg * 8]);
            bl[ni] = *reinterpret_cast<const short8v*>(&sBl[r * TBK + kg * 8]);
        }
#pragma unroll
        for (int mi = 0; mi < 4; ++mi)
#pragma unroll
            for (int ni = 0; ni < 4; ++ni) {
                acc[mi][ni] = MFMA(ah[mi], bh[ni], acc[mi][ni]);
                acc[mi][ni] = MFMA(ah[mi], bl[ni], acc[mi][ni]);
                acc[mi][ni] = MFMA(al[mi], bh[ni], acc[mi][ni]);
            }
        __syncthreads();
    }

    // C/D layout (m89-verified): col = lane&15, row = (lane>>4)*4 + reg
#pragma unroll
    for (int mi = 0; mi < 4; ++mi)
#pragma unroll
        for (int ni = 0; ni < 4; ++ni) {
            const int row = R0 + wm * 64 + mi * 16 + kg * 4;
            const int col = c0 + wn * 64 + ni * 16 + fr;
            float* cp = C + (size_t)row * 512 + col;
            cp[0]        = acc[mi][ni][0];
            cp[512]      = acc[mi][ni][1];
            cp[1024]     = acc[mi][ni][2];
            cp[1536]     = acc[mi][ni][3];
        }
}

// ---------------------------------------------------------------------------
// Weight pre-processing: W[K][512] fp32 -> Bt_h/Bt_l [512][K] bf16 (split+T)
// ---------------------------------------------------------------------------
__global__ __launch_bounds__(256)
void conv_w_split(const float* __restrict__ W, short* __restrict__ Bth,
                  short* __restrict__ Btl, int K) {
    const int idx = blockIdx.x * 256 + threadIdx.x;
    if (idx >= K * 512) return;
    const int k = idx >> 9, n = idx & 511;
    short h, l;
    split_bf16(W[idx], h, l);
    Bth[(size_t)n * K + k] = h;
    Btl[(size_t)n * K + k] = l;
}

__device__ __forceinline__ float leaky(float x) {
    return x >= 0.f ? x : NEG_SLOPE * x;
}
__device__ __forceinline__ float dot4(float4 a, float4 b) {
    return a.x * b.x + a.y * b.y + a.z * b.z + a.w * b.w;
}

// ---------------------------------------------------------------------------
// Fused attention: dots (src/dst einsum) + chain softmax + combine + bias
// (+ReLU). One wave per node; the wave already loads full xp rows for v and
// v-1, so the dots are computed in-register (kills the separate att_dots pass).
// ---------------------------------------------------------------------------
__global__ __launch_bounds__(256)
void att_combine_fused(const float* __restrict__ xp, const float* __restrict__ att_src,
                       const float* __restrict__ att_dst, const float* __restrict__ bias,
                       float* __restrict__ hout, int do_relu) {
    const int v = blockIdx.x * 4 + (threadIdx.x >> 6);
    const int lane = threadIdx.x & 63;
    const int j = v & (NNODE - 1);

    const float4 xv0 = *reinterpret_cast<const float4*>(&xp[(size_t)v * 512 + lane * 4]);
    const float4 xv1 = *reinterpret_cast<const float4*>(&xp[(size_t)v * 512 + 256 + lane * 4]);
    const float4 s0 = *reinterpret_cast<const float4*>(&att_src[lane * 4]);
    const float4 s1 = *reinterpret_cast<const float4*>(&att_src[256 + lane * 4]);
    const float4 d0 = *reinterpret_cast<const float4*>(&att_dst[lane * 4]);
    const float4 d1 = *reinterpret_cast<const float4*>(&att_dst[256 + lane * 4]);

    float vs0 = dot4(xv0, s0), vs1 = dot4(xv1, s1);
    float vd0 = dot4(xv0, d0), vd1 = dot4(xv1, d1);
    float ps0 = 0.f, ps1 = 0.f;
    float4 xq0 = {0.f, 0.f, 0.f, 0.f}, xq1 = {0.f, 0.f, 0.f, 0.f};
    if (j > 0) {
        xq0 = *reinterpret_cast<const float4*>(&xp[(size_t)(v - 1) * 512 + lane * 4]);
        xq1 = *reinterpret_cast<const float4*>(&xp[(size_t)(v - 1) * 512 + 256 + lane * 4]);
        ps0 = dot4(xq0, s0);
        ps1 = dot4(xq1, s1);
    }
#pragma unroll
    for (int off = 32; off; off >>= 1) {
        vs0 += __shfl_xor(vs0, off); vs1 += __shfl_xor(vs1, off);
        vd0 += __shfl_xor(vd0, off); vd1 += __shfl_xor(vd1, off);
        ps0 += __shfl_xor(ps0, off); ps1 += __shfl_xor(ps1, off);
    }

    float ain0 = 0.f, ain1 = 0.f, asf0 = 1.f, asf1 = 1.f;
    if (j > 0) {
        {   // head 0
            const float ein = leaky(ps0 + vd0);
            const float esf = leaky(vs0 + vd0);
            const float m = fmaxf(ein, esf);
            const float win = expf(ein - m), wsf = expf(esf - m);
            const float den = win + wsf + 1e-16f;
            ain0 = win / den; asf0 = wsf / den;
        }
        {   // head 1
            const float ein = leaky(ps1 + vd1);
            const float esf = leaky(vs1 + vd1);
            const float m = fmaxf(ein, esf);
            const float win = expf(ein - m), wsf = expf(esf - m);
            const float den = win + wsf + 1e-16f;
            ain1 = win / den; asf1 = wsf / den;
        }
    }

    const float4 bb = *reinterpret_cast<const float4*>(&bias[lane * 4]);
    float4 r;
    r.x = 0.5f * (ain0 * xq0.x + asf0 * xv0.x + ain1 * xq1.x + asf1 * xv1.x) + bb.x;
    r.y = 0.5f * (ain0 * xq0.y + asf0 * xv0.y + ain1 * xq1.y + asf1 * xv1.y) + bb.y;
    r.z = 0.5f * (ain0 * xq0.z + asf0 * xv0.z + ain1 * xq1.z + asf1 * xv1.z) + bb.z;
    r.w = 0.5f * (ain0 * xq0.w + asf0 * xv0.w + ain1 * xq1.w + asf1 * xv1.w) + bb.w;
    if (do_relu) {
        r.x = fmaxf(r.x, 0.f); r.y = fmaxf(r.y, 0.f);
        r.z = fmaxf(r.z, 0.f); r.w = fmaxf(r.w, 0.f);
    }
    *reinterpret_cast<float4*>(&hout[(size_t)v * 256 + lane * 4]) = r;
}

// ---------------------------------------------------------------------------
// SAGPool score (chain GraphConv): score[v] = h[v].pW_root + [j>0] h[v-1].pW_rel + pb
// ---------------------------------------------------------------------------
__global__ __launch_bounds__(256)
void score_kernel(const float* __restrict__ h, const float* __restrict__ pW_root,
                  const float* __restrict__ pW_rel, const float* __restrict__ pb,
                  float* __restrict__ score) {
    const int v = blockIdx.x * 4 + (threadIdx.x >> 6);
    const int lane = threadIdx.x & 63;
    const int j = v & (NNODE - 1);

    const float4 hv = *reinterpret_cast<const float4*>(&h[(size_t)v * 256 + lane * 4]);
    const float4 wr = *reinterpret_cast<const float4*>(&pW_root[lane * 4]);
    float s = dot4(hv, wr);
    if (j > 0) {
        const float4 hp = *reinterpret_cast<const float4*>(&h[(size_t)(v - 1) * 256 + lane * 4]);
        const float4 wl = *reinterpret_cast<const float4*>(&pW_rel[lane * 4]);
        s += dot4(hp, wl);
    }
#pragma unroll
    for (int off = 32; off; off >>= 1) s += __shfl_xor(s, off);
    if (lane == 0) score[v] = s + pb[0];
}

// ---------------------------------------------------------------------------
// Per-graph top-K (bitonic, lax.top_k tie-order), gated mean pool, classifier.
// ---------------------------------------------------------------------------
__global__ __launch_bounds__(1024)
void topk_pool(const float* __restrict__ score, const float* __restrict__ h,
               const float* __restrict__ cls_W, const float* __restrict__ cls_b,
               float* __restrict__ out) {
    __shared__ unsigned long long keys[NNODE];
    __shared__ float sc[NNODE];
    __shared__ float partial[4][256];
    __shared__ float red[8];

    const int b = blockIdx.x;
    const int tid = threadIdx.x;

    for (int i = tid; i < NNODE; i += 1024) {
        float v = score[(size_t)b * NNODE + i];
        sc[i] = v;
        unsigned u = __float_as_uint(v);
        u = (u & 0x80000000u) ? ~u : (u | 0x80000000u);
        keys[i] = ((unsigned long long)(~u) << 32) | (unsigned)i;
    }
    __syncthreads();

    for (int k = 2; k <= NNODE; k <<= 1) {
        for (int jj = k >> 1; jj > 0; jj >>= 1) {
            int i = ((tid & ~(jj - 1)) << 1) | (tid & (jj - 1));
            int ixj = i | jj;
            unsigned long long a = keys[i], c = keys[ixj];
            bool up = ((i & k) == 0);
            if ((a > c) == up) { keys[i] = c; keys[ixj] = a; }
            __syncthreads();
        }
    }

    const int g = tid >> 8;
    const int c = tid & 255;
    float acc = 0.f;
    for (int kk = g; kk < KKEEP; kk += 4) {
        int idx = (int)(keys[kk] & 0xffffffffu);
        float gate = tanhf(sc[idx]);
        acc += h[((size_t)b * NNODE + idx) * 256 + c] * gate;
    }
    partial[g][c] = acc;
    __syncthreads();

    if (tid < 256) {
        float pooled = (partial[0][tid] + partial[1][tid] +
                        partial[2][tid] + partial[3][tid]) / (float)KKEEP;
        float p0 = pooled * cls_W[tid * 2 + 0];
        float p1 = pooled * cls_W[tid * 2 + 1];
#pragma unroll
        for (int off = 32; off; off >>= 1) {
            p0 += __shfl_down(p0, off);
            p1 += __shfl_down(p1, off);
        }
        if ((tid & 63) == 0) {
            red[(tid >> 6) * 2 + 0] = p0;
            red[(tid >> 6) * 2 + 1] = p1;
        }
    }
    __syncthreads();
    if (tid == 0) {
        out[b * 2 + 0] = red[0] + red[2] + red[4] + red[6] + cls_b[0];
        out[b * 2 + 1] = red[1] + red[3] + red[5] + red[7] + cls_b[1];
    }
}

// ---------------------------------------------------------------------------

extern "C" void kernel_launch(void* const* d_in, const int* in_sizes, int n_in,
                              void* d_out, int out_size, void* d_ws, size_t ws_size,
                              hipStream_t stream) {
    const float* x        = (const float*)d_in[0];
    const float* W1       = (const float*)d_in[1];
    const float* att_src1 = (const float*)d_in[2];
    const float* att_dst1 = (const float*)d_in[3];
    const float* b1       = (const float*)d_in[4];
    const float* W2       = (const float*)d_in[5];
    const float* att_src2 = (const float*)d_in[6];
    const float* att_dst2 = (const float*)d_in[7];
    const float* b2       = (const float*)d_in[8];
    const float* pW_root  = (const float*)d_in[9];
    const float* pW_rel   = (const float*)d_in[10];
    const float* pb       = (const float*)d_in[11];
    const float* cls_W    = (const float*)d_in[12];
    const float* cls_b    = (const float*)d_in[13];
    float* out = (float*)d_out;

    // workspace (~405 MB, same footprint as the passing round-2 layout):
    float* xp     = (float*)d_ws;              // NT*512 fp32
    float* hbuf   = xp + (size_t)NT * 512;     // NT*256 fp32
    float* scores = hbuf + (size_t)NT * 256;   // NT fp32
    short* Bt1h   = (short*)(scores + NT);     // 512*512 bf16
    short* Bt1l   = Bt1h + 512 * 512;
    short* Bt2h   = Bt1l + 512 * 512;          // 512*256 bf16
    short* Bt2l   = Bt2h + 512 * 256;

    const int gemm_grid = (NT / TBM) * (512 / TBN);   // 1024 * 4 = 4096
    const int nwave_blocks = NT / 4;                  // 32768

    // weight split+transpose (tiny)
    conv_w_split<<<(512 * 512 + 255) / 256, 256, 0, stream>>>(W1, Bt1h, Bt1l, 512);
    conv_w_split<<<(256 * 512 + 255) / 256, 256, 0, stream>>>(W2, Bt2h, Bt2l, 256);

    // ---- layer 1
    gemm_split_bf16<<<gemm_grid, 256, 0, stream>>>(x, Bt1h, Bt1l, xp, 512);
    att_combine_fused<<<nwave_blocks, 256, 0, stream>>>(xp, att_src1, att_dst1, b1, hbuf, 1);

    // ---- layer 2
    gemm_split_bf16<<<gemm_grid, 256, 0, stream>>>(hbuf, Bt2h, Bt2l, xp, 256);
    att_combine_fused<<<nwave_blocks, 256, 0, stream>>>(xp, att_src2, att_dst2, b2, hbuf, 0);

    // ---- SAGPool + classifier
    score_kernel<<<nwave_blocks, 256, 0, stream>>>(hbuf, pW_root, pW_rel, pb, scores);
    topk_pool<<<NGRAPH, 1024, 0, stream>>>(scores, hbuf, cls_W, cls_b, out);
}

// Round 4
// 593.349 us; speedup vs baseline: 2.5777x; 1.0786x over previous
//
#include <hip/hip_runtime.h>
#include <hip/hip_bf16.h>
#include <stdint.h>

#define NGRAPH 64
#define NNODE  2048
#define NT     (NGRAPH * NNODE)   // 131072
#define KKEEP  410
#define NEG_SLOPE 0.2f

typedef __attribute__((ext_vector_type(4))) float  f32x4;
typedef __attribute__((ext_vector_type(8))) short  short8v;
typedef __attribute__((ext_vector_type(8))) __bf16 bf16x8;

// ---------------------------------------------------------------------------
// MFMA 16x16x32 bf16 — SFINAE tag-dispatch over the builtin's operand type.
// ---------------------------------------------------------------------------
template <typename A>
__device__ __forceinline__ auto mfma_call(A a, A b, f32x4 c, int)
    -> decltype(__builtin_amdgcn_mfma_f32_16x16x32_bf16(a, b, c, 0, 0, 0)) {
    return __builtin_amdgcn_mfma_f32_16x16x32_bf16(a, b, c, 0, 0, 0);
}
template <typename A>
__device__ __forceinline__ f32x4 mfma_call(A a, A b, f32x4 c, long) {
    return __builtin_amdgcn_mfma_f32_16x16x32_bf16(
        __builtin_bit_cast(bf16x8, a), __builtin_bit_cast(bf16x8, b), c, 0, 0, 0);
}
__device__ __forceinline__ f32x4 MFMA(short8v a, short8v b, f32x4 c) {
    return mfma_call(a, b, c, 0);
}

// split x = hi + lo (bf16 RNE; x-hi exact; bf16 exponent range = f32)
__device__ __forceinline__ void split_bf16(float x, short& hi, short& lo) {
    __bf16 h = (__bf16)x;
    float  hf = (float)h;
    __bf16 l = (__bf16)(x - hf);
    hi = __builtin_bit_cast(short, h);
    lo = __builtin_bit_cast(short, l);
}
__device__ __forceinline__ unsigned pack_split(float x) {
    short h, l;
    split_bf16(x, h, l);
    return ((unsigned)(unsigned short)h << 16) | (unsigned)(unsigned short)l;
}

__device__ __forceinline__ void gload16(const void* g, void* lds) {
    __builtin_amdgcn_global_load_lds(
        (const __attribute__((address_space(1))) void*)g,
        (__attribute__((address_space(3))) void*)lds,
        16, 0, 0);
}

// ---------------------------------------------------------------------------
// Split-bf16 MFMA GEMM, 256x256xBK32 tile, 8 waves (2x4, wave-tile 128x64).
//   C = Ah@Bh + Ah@Bl + Al@Bh (fp32 MFMA accumulate), C[M,512].
// Early-issue double-buffered pipeline, __syncthreads-only (race-safe):
//   iter t: issue gload_lds B(t+1)->buf^1 + global A(t+1)->regs,
//           ds_read frags(buf) + 96 MFMA, split/ds_write A(t+1)->buf^1, barrier.
// LDS XOR swizzle (slot ^= (row>>1)&3 on 64B rows): A swizzled on write+read;
// B swizzled via pre-swizzled per-lane GLOBAL source (gload_lds dest linear).
// APACK=1: A elements are (bf16hi<<16)|bf16lo packed u32 (pre-split h1).
// ---------------------------------------------------------------------------
#define GBM 256
#define GBN 256
#define GBK 32
// LDS per buffer: Ah 16K | Al 16K | Bh 16K | Bl 16K ; 2 buffers = 128 KiB
#define LDS_BUF 65536
#define OFF_AL  16384
#define OFF_BH  32768
#define OFF_BL  49152

template <int APACK>
__global__ __launch_bounds__(512, 2)
void gemm256(const void* __restrict__ Av, const short* __restrict__ Bth,
             const short* __restrict__ Btl, float* __restrict__ C, int Kd) {
    extern __shared__ char smem[];
    const int tid  = threadIdx.x;
    const int lane = tid & 63;
    const int w    = tid >> 6;          // wave 0..7
    const int wm   = w >> 2, wn = w & 3;

    // XCD-aware bijective swizzle (grid 1024 %8==0); wg,wg+1 share the A-panel.
    const int cpx = (int)gridDim.x >> 3;
    const int wg  = ((int)blockIdx.x & 7) * cpx + ((int)blockIdx.x >> 3);
    const int bx = wg & 1, by = wg >> 1;
    const int R0 = by * GBM, c0 = bx * GBN;

    const int fr = lane & 15, kg = lane >> 4;
    const int nk = Kd / GBK;

    f32x4 acc[8][4];
#pragma unroll
    for (int m = 0; m < 8; ++m)
#pragma unroll
        for (int n = 0; n < 4; ++n) acc[m][n] = (f32x4)(0.0f);

    // A chunk map: 256x32 elems (4B each) = 2048 dwordx4 chunks; thread gets
    // chunks tid+512i -> row = (tid>>3)+64i, q = tid&7 (k-offset q*4).
    const int arow0 = tid >> 3;
    const int aq    = tid & 7;

    uint4 areg[4];

    auto issueB = [&](int t, int buf) {
        char* bh = smem + buf * LDS_BUF + OFF_BH;
        char* bl = smem + buf * LDS_BUF + OFF_BL;
#pragma unroll
        for (int i = 0; i < 2; ++i) {
            const int rl = w * 32 + i * 16 + (lane >> 2);     // LDS row 0..255
            const int ks = (lane & 3) ^ ((rl >> 1) & 3);      // pre-swizzled k-slot
            const size_t go = (size_t)(c0 + rl) * Kd + (size_t)t * GBK + ks * 8;
            gload16(Bth + go, bh + (w * 32 + i * 16) * 64);
            gload16(Btl + go, bl + (w * 32 + i * 16) * 64);
        }
    };
    auto loadA = [&](int t) {
        const unsigned* A = (const unsigned*)Av;
#pragma unroll
        for (int i = 0; i < 4; ++i)
            areg[i] = *reinterpret_cast<const uint4*>(
                &A[(size_t)(R0 + arow0 + 64 * i) * Kd + (size_t)t * GBK + aq * 4]);
    };
    auto writeA = [&](int buf) {
        char* ahp = smem + buf * LDS_BUF;
        char* alp = ahp + OFF_AL;
#pragma unroll
        for (int i = 0; i < 4; ++i) {
            short4 hh, ll;
            const unsigned u[4] = {areg[i].x, areg[i].y, areg[i].z, areg[i].w};
            short hs[4], ls[4];
#pragma unroll
            for (int e = 0; e < 4; ++e) {
                if (APACK) {
                    hs[e] = (short)(u[e] >> 16);
                    ls[e] = (short)(u[e] & 0xffffu);
                } else {
                    split_bf16(__builtin_bit_cast(float, u[e]), hs[e], ls[e]);
                }
            }
            hh.x = hs[0]; hh.y = hs[1]; hh.z = hs[2]; hh.w = hs[3];
            ll.x = ls[0]; ll.y = ls[1]; ll.z = ls[2]; ll.w = ls[3];
            const int row  = arow0 + 64 * i;
            const int byte = row * 64 + (((aq >> 1) ^ ((row >> 1) & 3)) << 4) + (aq & 1) * 8;
            *reinterpret_cast<short4*>(ahp + byte) = hh;
            *reinterpret_cast<short4*>(alp + byte) = ll;
        }
    };

    // prologue: stage tile 0
    issueB(0, 0);
    loadA(0);
    writeA(0);
    __syncthreads();

    for (int t = 0; t < nk; ++t) {
        const int cur = t & 1, nxt = cur ^ 1;
        if (t + 1 < nk) { issueB(t + 1, nxt); loadA(t + 1); }

        const char* pAh = smem + cur * LDS_BUF;
        const char* pAl = pAh + OFF_AL;
        const char* pBh = pAh + OFF_BH;
        const char* pBl = pAh + OFF_BL;

        short8v bhf[4], blf[4];
#pragma unroll
        for (int n = 0; n < 4; ++n) {
            const int rl   = wn * 64 + n * 16 + fr;
            const int byte = rl * 64 + ((kg ^ ((rl >> 1) & 3)) << 4);
            bhf[n] = *reinterpret_cast<const short8v*>(pBh + byte);
            blf[n] = *reinterpret_cast<const short8v*>(pBl + byte);
        }
        __builtin_amdgcn_s_setprio(1);
#pragma unroll
        for (int m = 0; m < 8; ++m) {
            const int rl   = wm * 128 + m * 16 + fr;
            const int byte = rl * 64 + ((kg ^ ((rl >> 1) & 3)) << 4);
            const short8v ah = *reinterpret_cast<const short8v*>(pAh + byte);
            const short8v al = *reinterpret_cast<const short8v*>(pAl + byte);
#pragma unroll
            for (int n = 0; n < 4; ++n) {
                acc[m][n] = MFMA(ah, bhf[n], acc[m][n]);
                acc[m][n] = MFMA(ah, blf[n], acc[m][n]);
                acc[m][n] = MFMA(al, bhf[n], acc[m][n]);
            }
        }
        __builtin_amdgcn_s_setprio(0);

        if (t + 1 < nk) writeA(nxt);
        __syncthreads();
    }

    // C/D layout (m89-verified, round-3-proven): col = lane&15, row = kg*4+reg
#pragma unroll
    for (int m = 0; m < 8; ++m)
#pragma unroll
        for (int n = 0; n < 4; ++n) {
            const int row = R0 + wm * 128 + m * 16 + kg * 4;
            const int col = c0 + wn * 64 + n * 16 + fr;
            float* cp = C + (size_t)row * 512 + col;
            cp[0]    = acc[m][n][0];
            cp[512]  = acc[m][n][1];
            cp[1024] = acc[m][n][2];
            cp[1536] = acc[m][n][3];
        }
}

// ---------------------------------------------------------------------------
// Weight pre-processing: W[K][512] fp32 -> Bt_h/Bt_l [512][K] bf16 (split+T)
// ---------------------------------------------------------------------------
__global__ __launch_bounds__(256)
void conv_w_split(const float* __restrict__ W, short* __restrict__ Bth,
                  short* __restrict__ Btl, int K) {
    const int idx = blockIdx.x * 256 + threadIdx.x;
    if (idx >= K * 512) return;
    const int k = idx >> 9, n = idx & 511;
    short h, l;
    split_bf16(W[idx], h, l);
    Bth[(size_t)n * K + k] = h;
    Btl[(size_t)n * K + k] = l;
}

__device__ __forceinline__ float leaky(float x) {
    return x >= 0.f ? x : NEG_SLOPE * x;
}
__device__ __forceinline__ float dot4(float4 a, float4 b) {
    return a.x * b.x + a.y * b.y + a.z * b.z + a.w * b.w;
}

// ---------------------------------------------------------------------------
// Fused attention: dots + chain softmax + combine + bias (+ReLU).
// PACKOUT=1: write h as packed split-pair u32 (consumed only by gemm256<1>).
// ---------------------------------------------------------------------------
template <int PACKOUT>
__global__ __launch_bounds__(256)
void att_combine_fused(const float* __restrict__ xp, const float* __restrict__ att_src,
                       const float* __restrict__ att_dst, const float* __restrict__ bias,
                       void* __restrict__ hout, int do_relu) {
    const int v = blockIdx.x * 4 + (threadIdx.x >> 6);
    const int lane = threadIdx.x & 63;
    const int j = v & (NNODE - 1);

    const float4 xv0 = *reinterpret_cast<const float4*>(&xp[(size_t)v * 512 + lane * 4]);
    const float4 xv1 = *reinterpret_cast<const float4*>(&xp[(size_t)v * 512 + 256 + lane * 4]);
    const float4 s0 = *reinterpret_cast<const float4*>(&att_src[lane * 4]);
    const float4 s1 = *reinterpret_cast<const float4*>(&att_src[256 + lane * 4]);
    const float4 d0 = *reinterpret_cast<const float4*>(&att_dst[lane * 4]);
    const float4 d1 = *reinterpret_cast<const float4*>(&att_dst[256 + lane * 4]);

    float vs0 = dot4(xv0, s0), vs1 = dot4(xv1, s1);
    float vd0 = dot4(xv0, d0), vd1 = dot4(xv1, d1);
    float ps0 = 0.f, ps1 = 0.f;
    float4 xq0 = {0.f, 0.f, 0.f, 0.f}, xq1 = {0.f, 0.f, 0.f, 0.f};
    if (j > 0) {
        xq0 = *reinterpret_cast<const float4*>(&xp[(size_t)(v - 1) * 512 + lane * 4]);
        xq1 = *reinterpret_cast<const float4*>(&xp[(size_t)(v - 1) * 512 + 256 + lane * 4]);
        ps0 = dot4(xq0, s0);
        ps1 = dot4(xq1, s1);
    }
#pragma unroll
    for (int off = 32; off; off >>= 1) {
        vs0 += __shfl_xor(vs0, off); vs1 += __shfl_xor(vs1, off);
        vd0 += __shfl_xor(vd0, off); vd1 += __shfl_xor(vd1, off);
        ps0 += __shfl_xor(ps0, off); ps1 += __shfl_xor(ps1, off);
    }

    float ain0 = 0.f, ain1 = 0.f, asf0 = 1.f, asf1 = 1.f;
    if (j > 0) {
        {
            const float ein = leaky(ps0 + vd0);
            const float esf = leaky(vs0 + vd0);
            const float m = fmaxf(ein, esf);
            const float win = expf(ein - m), wsf = expf(esf - m);
            const float den = win + wsf + 1e-16f;
            ain0 = win / den; asf0 = wsf / den;
        }
        {
            const float ein = leaky(ps1 + vd1);
            const float esf = leaky(vs1 + vd1);
            const float m = fmaxf(ein, esf);
            const float win = expf(ein - m), wsf = expf(esf - m);
            const float den = win + wsf + 1e-16f;
            ain1 = win / den; asf1 = wsf / den;
        }
    }

    const float4 bb = *reinterpret_cast<const float4*>(&bias[lane * 4]);
    float4 r;
    r.x = 0.5f * (ain0 * xq0.x + asf0 * xv0.x + ain1 * xq1.x + asf1 * xv1.x) + bb.x;
    r.y = 0.5f * (ain0 * xq0.y + asf0 * xv0.y + ain1 * xq1.y + asf1 * xv1.y) + bb.y;
    r.z = 0.5f * (ain0 * xq0.z + asf0 * xv0.z + ain1 * xq1.z + asf1 * xv1.z) + bb.z;
    r.w = 0.5f * (ain0 * xq0.w + asf0 * xv0.w + ain1 * xq1.w + asf1 * xv1.w) + bb.w;
    if (do_relu) {
        r.x = fmaxf(r.x, 0.f); r.y = fmaxf(r.y, 0.f);
        r.z = fmaxf(r.z, 0.f); r.w = fmaxf(r.w, 0.f);
    }
    if (PACKOUT) {
        uint4 o;
        o.x = pack_split(r.x); o.y = pack_split(r.y);
        o.z = pack_split(r.z); o.w = pack_split(r.w);
        *reinterpret_cast<uint4*>((unsigned*)hout + (size_t)v * 256 + lane * 4) = o;
    } else {
        *reinterpret_cast<float4*>((float*)hout + (size_t)v * 256 + lane * 4) = r;
    }
}

// ---------------------------------------------------------------------------
// SAGPool score: score[v] = h[v].pW_root + [j>0] h[v-1].pW_rel + pb
// ---------------------------------------------------------------------------
__global__ __launch_bounds__(256)
void score_kernel(const float* __restrict__ h, const float* __restrict__ pW_root,
                  const float* __restrict__ pW_rel, const float* __restrict__ pb,
                  float* __restrict__ score) {
    const int v = blockIdx.x * 4 + (threadIdx.x >> 6);
    const int lane = threadIdx.x & 63;
    const int j = v & (NNODE - 1);

    const float4 hv = *reinterpret_cast<const float4*>(&h[(size_t)v * 256 + lane * 4]);
    const float4 wr = *reinterpret_cast<const float4*>(&pW_root[lane * 4]);
    float s = dot4(hv, wr);
    if (j > 0) {
        const float4 hp = *reinterpret_cast<const float4*>(&h[(size_t)(v - 1) * 256 + lane * 4]);
        const float4 wl = *reinterpret_cast<const float4*>(&pW_rel[lane * 4]);
        s += dot4(hp, wl);
    }
#pragma unroll
    for (int off = 32; off; off >>= 1) s += __shfl_xor(s, off);
    if (lane == 0) score[v] = s + pb[0];
}

// ---------------------------------------------------------------------------
// Per-graph top-K (bitonic, lax.top_k tie-order), gated mean pool, classifier.
// ---------------------------------------------------------------------------
__global__ __launch_bounds__(1024)
void topk_pool(const float* __restrict__ score, const float* __restrict__ h,
               const float* __restrict__ cls_W, const float* __restrict__ cls_b,
               float* __restrict__ out) {
    __shared__ unsigned long long keys[NNODE];
    __shared__ float sc[NNODE];
    __shared__ float partial[4][256];
    __shared__ float red[8];

    const int b = blockIdx.x;
    const int tid = threadIdx.x;

    for (int i = tid; i < NNODE; i += 1024) {
        float v = score[(size_t)b * NNODE + i];
        sc[i] = v;
        unsigned u = __float_as_uint(v);
        u = (u & 0x80000000u) ? ~u : (u | 0x80000000u);
        keys[i] = ((unsigned long long)(~u) << 32) | (unsigned)i;
    }
    __syncthreads();

    for (int k = 2; k <= NNODE; k <<= 1) {
        for (int jj = k >> 1; jj > 0; jj >>= 1) {
            int i = ((tid & ~(jj - 1)) << 1) | (tid & (jj - 1));
            int ixj = i | jj;
            unsigned long long a = keys[i], c = keys[ixj];
            bool up = ((i & k) == 0);
            if ((a > c) == up) { keys[i] = c; keys[ixj] = a; }
            __syncthreads();
        }
    }

    const int g = tid >> 8;
    const int c = tid & 255;
    float acc = 0.f;
    for (int kk = g; kk < KKEEP; kk += 4) {
        int idx = (int)(keys[kk] & 0xffffffffu);
        float gate = tanhf(sc[idx]);
        acc += h[((size_t)b * NNODE + idx) * 256 + c] * gate;
    }
    partial[g][c] = acc;
    __syncthreads();

    if (tid < 256) {
        float pooled = (partial[0][tid] + partial[1][tid] +
                        partial[2][tid] + partial[3][tid]) / (float)KKEEP;
        float p0 = pooled * cls_W[tid * 2 + 0];
        float p1 = pooled * cls_W[tid * 2 + 1];
#pragma unroll
        for (int off = 32; off; off >>= 1) {
            p0 += __shfl_down(p0, off);
            p1 += __shfl_down(p1, off);
        }
        if ((tid & 63) == 0) {
            red[(tid >> 6) * 2 + 0] = p0;
            red[(tid >> 6) * 2 + 1] = p1;
        }
    }
    __syncthreads();
    if (tid == 0) {
        out[b * 2 + 0] = red[0] + red[2] + red[4] + red[6] + cls_b[0];
        out[b * 2 + 1] = red[1] + red[3] + red[5] + red[7] + cls_b[1];
    }
}

// ---------------------------------------------------------------------------

extern "C" void kernel_launch(void* const* d_in, const int* in_sizes, int n_in,
                              void* d_out, int out_size, void* d_ws, size_t ws_size,
                              hipStream_t stream) {
    const float* x        = (const float*)d_in[0];
    const float* W1       = (const float*)d_in[1];
    const float* att_src1 = (const float*)d_in[2];
    const float* att_dst1 = (const float*)d_in[3];
    const float* b1       = (const float*)d_in[4];
    const float* W2       = (const float*)d_in[5];
    const float* att_src2 = (const float*)d_in[6];
    const float* att_dst2 = (const float*)d_in[7];
    const float* b2       = (const float*)d_in[8];
    const float* pW_root  = (const float*)d_in[9];
    const float* pW_rel   = (const float*)d_in[10];
    const float* pb       = (const float*)d_in[11];
    const float* cls_W    = (const float*)d_in[12];
    const float* cls_b    = (const float*)d_in[13];
    float* out = (float*)d_out;

    // workspace (~405 MB):
    float* xp     = (float*)d_ws;              // NT*512 f32
    float* hbuf   = xp + (size_t)NT * 512;     // NT*256 (u32 packed h1 / f32 h2)
    float* scores = hbuf + (size_t)NT * 256;   // NT f32
    short* Bt1h   = (short*)(scores + NT);     // 512*512 bf16
    short* Bt1l   = Bt1h + 512 * 512;
    short* Bt2h   = Bt1l + 512 * 512;          // 512*256 bf16
    short* Bt2l   = Bt2h + 512 * 256;

    const int gemm_grid = (NT / GBM) * (512 / GBN);   // 512 * 2 = 1024
    const int nwave_blocks = NT / 4;                  // 32768

    conv_w_split<<<(512 * 512 + 255) / 256, 256, 0, stream>>>(W1, Bt1h, Bt1l, 512);
    conv_w_split<<<(256 * 512 + 255) / 256, 256, 0, stream>>>(W2, Bt2h, Bt2l, 256);

    // ---- layer 1: xp = x @ W1 (split-bf16 MFMA); att -> h1 (packed split-pair)
    gemm256<0><<<gemm_grid, 512, 131072, stream>>>(x, Bt1h, Bt1l, xp, 512);
    att_combine_fused<1><<<nwave_blocks, 256, 0, stream>>>(xp, att_src1, att_dst1, b1, hbuf, 1);

    // ---- layer 2: xp = h1 @ W2 (A pre-split packed); att -> h2 (f32)
    gemm256<1><<<gemm_grid, 512, 131072, stream>>>(hbuf, Bt2h, Bt2l, xp, 256);
    att_combine_fused<0><<<nwave_blocks, 256, 0, stream>>>(xp, att_src2, att_dst2, b2, hbuf, 0);

    // ---- SAGPool + classifier
    score_kernel<<<nwave_blocks, 256, 0, stream>>>(hbuf, pW_root, pW_rel, pb, scores);
    topk_pool<<<NGRAPH, 1024, 0, stream>>>(scores, hbuf, cls_W, cls_b, out);
}

// Round 5
// 517.559 us; speedup vs baseline: 2.9551x; 1.1464x over previous
//
#include <hip/hip_runtime.h>
#include <hip/hip_bf16.h>
#include <stdint.h>

#define NGRAPH 64
#define NNODE  2048
#define NT     (NGRAPH * NNODE)   // 131072
#define KKEEP  410
#define NEG_SLOPE 0.2f

typedef __attribute__((ext_vector_type(4))) float  f32x4;
typedef __attribute__((ext_vector_type(8))) short  short8v;
typedef __attribute__((ext_vector_type(8))) __bf16 bf16x8;

// ---------------------------------------------------------------------------
// MFMA 16x16x32 bf16 — SFINAE tag-dispatch over the builtin's operand type.
// ---------------------------------------------------------------------------
template <typename A>
__device__ __forceinline__ auto mfma_call(A a, A b, f32x4 c, int)
    -> decltype(__builtin_amdgcn_mfma_f32_16x16x32_bf16(a, b, c, 0, 0, 0)) {
    return __builtin_amdgcn_mfma_f32_16x16x32_bf16(a, b, c, 0, 0, 0);
}
template <typename A>
__device__ __forceinline__ f32x4 mfma_call(A a, A b, f32x4 c, long) {
    return __builtin_amdgcn_mfma_f32_16x16x32_bf16(
        __builtin_bit_cast(bf16x8, a), __builtin_bit_cast(bf16x8, b), c, 0, 0, 0);
}
__device__ __forceinline__ f32x4 MFMA(short8v a, short8v b, f32x4 c) {
    return mfma_call(a, b, c, 0);
}

// split x = hi + lo (bf16 RNE; x-hi exact; bf16 exponent range = f32)
__device__ __forceinline__ void split_bf16(float x, short& hi, short& lo) {
    __bf16 h = (__bf16)x;
    float  hf = (float)h;
    __bf16 l = (__bf16)(x - hf);
    hi = __builtin_bit_cast(short, h);
    lo = __builtin_bit_cast(short, l);
}

__device__ __forceinline__ void gload16(const void* g, void* lds) {
    __builtin_amdgcn_global_load_lds(
        (const __attribute__((address_space(1))) void*)g,
        (__attribute__((address_space(3))) void*)lds,
        16, 0, 0);
}

__device__ __forceinline__ float leaky(float x) {
    return x >= 0.f ? x : NEG_SLOPE * x;
}
__device__ __forceinline__ float dot4(float4 a, float4 b) {
    return a.x * b.x + a.y * b.y + a.z * b.z + a.w * b.w;
}

// ---------------------------------------------------------------------------
// Fused GAT-layer GEMM:  H[v,:256] = act( sum_h (ain_h*A[v-1]+asf_h*A[v]) @ W_h + bias )
// as one K-concatenated split-bf16 MFMA GEMM.
//   A: [NT, Kx] fp32 (x or h1).  Kcat = 2*Kx; K index kk = xblk*64 + head*32 + c
//   Bth/Btl: [256][Kcat] bf16 (pre-split, head-interleaved, transposed).
//   alpha: [NT][4] = {ain_h0', asf_h0', ain_h1', asf_h1'} (0.5 head-mean folded).
// Tile 256 rows x 256 cols (full N) x BK32, 8 waves (2x4), wave-tile 128x64.
// Early-issue double-buffered (round-4-proven schedule + swizzles).
// Epilogue: bias (+ReLU), write H; per-row partial dots with wv[NVEC][256]
// (cross-wave LDS reduce) -> dout[v][NVEC]  (dots2 for layer1 / SAG score pair
// for layer2) — kills the separate dots/score passes.
// ---------------------------------------------------------------------------
#define GBM 256
#define GBK 32
#define LDS_BUF 65536
#define OFF_AL  16384
#define OFF_BH  32768
#define OFF_BL  49152

template <int NVEC, int RELU>
__global__ __launch_bounds__(512, 2)
void gemm_fused(const float* __restrict__ A, const short* __restrict__ Bth,
                const short* __restrict__ Btl, const float* __restrict__ alpha,
                const float* __restrict__ bias, const float* __restrict__ wv,
                float* __restrict__ H, float* __restrict__ dout, int Kcat) {
    extern __shared__ char smem[];
    const int tid  = threadIdx.x;
    const int lane = tid & 63;
    const int w    = tid >> 6;
    const int wm = w >> 2, wn = w & 3;
    const int R0 = (int)blockIdx.x * GBM;
    const int fr = lane & 15, kg = lane >> 4;
    const int nk = Kcat / GBK;
    const int Kx = Kcat >> 1;

    f32x4 acc[8][4];
#pragma unroll
    for (int m = 0; m < 8; ++m)
#pragma unroll
        for (int n = 0; n < 4; ++n) acc[m][n] = (f32x4)(0.0f);

    // A staging: 256x32 tile = 2048 f32x4 chunks; thread t: rows (t>>3)+64i, q=t&7
    const int arow0 = tid >> 3;
    const int aq    = tid & 7;

    int    prow[4];
    float4 aco[4];
    float4 xv[4], xp[4];
#pragma unroll
    for (int i = 0; i < 4; ++i) {
        const int gr = R0 + arow0 + 64 * i;
        prow[i] = ((gr & (NNODE - 1)) == 0) ? gr : gr - 1;   // clamp; ain'=0 there
        aco[i]  = *reinterpret_cast<const float4*>(&alpha[(size_t)gr * 4]);
    }

    auto issueB = [&](int t, int buf) {
        char* bh = smem + buf * LDS_BUF + OFF_BH;
        char* bl = smem + buf * LDS_BUF + OFF_BL;
#pragma unroll
        for (int i = 0; i < 2; ++i) {
            const int rl = w * 32 + i * 16 + (lane >> 2);
            const int ks = (lane & 3) ^ ((rl >> 1) & 3);
            const size_t go = (size_t)rl * Kcat + (size_t)t * GBK + ks * 8;
            gload16(Bth + go, bh + (w * 32 + i * 16) * 64);
            gload16(Btl + go, bl + (w * 32 + i * 16) * 64);
        }
    };
    auto loadX = [&](int xblk) {
        const int col = xblk * 32 + aq * 4;
#pragma unroll
        for (int i = 0; i < 4; ++i) {
            const int gr = R0 + arow0 + 64 * i;
            xv[i] = *reinterpret_cast<const float4*>(&A[(size_t)gr * Kx + col]);
            xp[i] = *reinterpret_cast<const float4*>(&A[(size_t)prow[i] * Kx + col]);
        }
    };
    auto writeA = [&](int tt, int buf) {
        char* ahp = smem + buf * LDS_BUF;
        char* alp = ahp + OFF_AL;
        const int hh = tt & 1;
#pragma unroll
        for (int i = 0; i < 4; ++i) {
            const float ain = hh ? aco[i].z : aco[i].x;
            const float asf = hh ? aco[i].w : aco[i].y;
            float y[4] = {ain * xp[i].x + asf * xv[i].x,
                          ain * xp[i].y + asf * xv[i].y,
                          ain * xp[i].z + asf * xv[i].z,
                          ain * xp[i].w + asf * xv[i].w};
            short4 hhv, llv;
            split_bf16(y[0], hhv.x, llv.x);
            split_bf16(y[1], hhv.y, llv.y);
            split_bf16(y[2], hhv.z, llv.z);
            split_bf16(y[3], hhv.w, llv.w);
            const int row  = arow0 + 64 * i;
            const int byte = row * 64 + (((aq >> 1) ^ ((row >> 1) & 3)) << 4) + (aq & 1) * 8;
            *reinterpret_cast<short4*>(ahp + byte) = hhv;
            *reinterpret_cast<short4*>(alp + byte) = llv;
        }
    };

    // prologue: stage tile 0 (head0 of xblk 0)
    issueB(0, 0);
    loadX(0);
    writeA(0, 0);
    __syncthreads();

    for (int t = 0; t < nk; ++t) {
        const int cur = t & 1, nxt = cur ^ 1;
        if (t + 1 < nk) {
            issueB(t + 1, nxt);
            if (((t + 1) & 1) == 0) loadX((t + 1) >> 1);  // odd tt reuses regs
        }

        const char* pAh = smem + cur * LDS_BUF;
        const char* pAl = pAh + OFF_AL;
        const char* pBh = pAh + OFF_BH;
        const char* pBl = pAh + OFF_BL;

        short8v bhf[4], blf[4];
#pragma unroll
        for (int n = 0; n < 4; ++n) {
            const int rl   = wn * 64 + n * 16 + fr;
            const int byte = rl * 64 + ((kg ^ ((rl >> 1) & 3)) << 4);
            bhf[n] = *reinterpret_cast<const short8v*>(pBh + byte);
            blf[n] = *reinterpret_cast<const short8v*>(pBl + byte);
        }
        __builtin_amdgcn_s_setprio(1);
#pragma unroll
        for (int m = 0; m < 8; ++m) {
            const int rl   = wm * 128 + m * 16 + fr;
            const int byte = rl * 64 + ((kg ^ ((rl >> 1) & 3)) << 4);
            const short8v ah = *reinterpret_cast<const short8v*>(pAh + byte);
            const short8v al = *reinterpret_cast<const short8v*>(pAl + byte);
#pragma unroll
            for (int n = 0; n < 4; ++n) {
                acc[m][n] = MFMA(ah, bhf[n], acc[m][n]);
                acc[m][n] = MFMA(ah, blf[n], acc[m][n]);
                acc[m][n] = MFMA(al, bhf[n], acc[m][n]);
            }
        }
        __builtin_amdgcn_s_setprio(0);

        if (t + 1 < nk) writeA(t + 1, nxt);
        __syncthreads();
    }

    // ---- epilogue: bias(+relu) -> H ; per-row partial dots with wv -> dout
    float bl4[4], wvl[NVEC][4];
#pragma unroll
    for (int n = 0; n < 4; ++n) {
        const int col = wn * 64 + n * 16 + fr;
        bl4[n] = bias[col];
#pragma unroll
        for (int v = 0; v < NVEC; ++v) wvl[v][n] = wv[v * 256 + col];
    }
    float* dbuf = (float*)smem;   // [256][NVEC][4wn], LDS free after final barrier

#pragma unroll
    for (int m = 0; m < 8; ++m) {
        float pd[4][NVEC];
#pragma unroll
        for (int r = 0; r < 4; ++r)
#pragma unroll
            for (int v = 0; v < NVEC; ++v) pd[r][v] = 0.f;

        const int rowb = wm * 128 + m * 16 + kg * 4;
#pragma unroll
        for (int n = 0; n < 4; ++n) {
            const int col = wn * 64 + n * 16 + fr;
            float* hp = H + (size_t)(R0 + rowb) * 256 + col;
#pragma unroll
            for (int r = 0; r < 4; ++r) {
                float hv = acc[m][n][r] + bl4[n];
                if (RELU) hv = fmaxf(hv, 0.f);
                hp[(size_t)r * 256] = hv;
#pragma unroll
                for (int v = 0; v < NVEC; ++v) pd[r][v] += hv * wvl[v][n];
            }
        }
#pragma unroll
        for (int r = 0; r < 4; ++r)
#pragma unroll
            for (int v = 0; v < NVEC; ++v) {
                float s = pd[r][v];
                s += __shfl_xor(s, 1);
                s += __shfl_xor(s, 2);
                s += __shfl_xor(s, 4);
                s += __shfl_xor(s, 8);
                if (fr == 0) dbuf[(rowb + r) * (NVEC * 4) + v * 4 + wn] = s;
            }
    }
    __syncthreads();
    if (tid < 256) {
#pragma unroll
        for (int v = 0; v < NVEC; ++v) {
            const float* d = &dbuf[tid * (NVEC * 4) + v * 4];
            dout[(size_t)(R0 + tid) * NVEC + v] = d[0] + d[1] + d[2] + d[3];
        }
    }
}

// ---------------------------------------------------------------------------
// prep: Bcat[n][kk] split/transposed, kk = xblk*64 + head*32 + c
// ---------------------------------------------------------------------------
__global__ __launch_bounds__(256)
void build_B(const float* __restrict__ W, short* __restrict__ Bth,
             short* __restrict__ Btl, int Kx) {
    const int Kcat = 2 * Kx;
    const int idx = blockIdx.x * 256 + threadIdx.x;
    if (idx >= 256 * Kcat) return;
    const int n = idx / Kcat, kk = idx % Kcat;
    const int xblk = kk >> 6, rem = kk & 63, head = rem >> 5, c = rem & 31;
    const int k = xblk * 32 + c;
    short h, l;
    split_bf16(W[(size_t)k * 512 + head * 256 + n], h, l);
    Bth[idx] = h;
    Btl[idx] = l;
}

// wvec[vec][k] = sum_c W[k][head*256+c] * att[head][c];  vec: 0,1=src h0,h1; 2,3=dst
__global__ __launch_bounds__(256)
void build_wvec(const float* __restrict__ W, const float* __restrict__ att_src,
                const float* __restrict__ att_dst, float* __restrict__ wvec, int K) {
    const int idx = blockIdx.x * 256 + threadIdx.x;
    if (idx >= 4 * K) return;
    const int vec = idx / K, k = idx % K;
    const int head = vec & 1;
    const float* att = (vec < 2) ? att_src : att_dst;
    float s = 0.f;
    for (int c = 0; c < 256; ++c)
        s += W[(size_t)k * 512 + head * 256 + c] * att[head * 256 + c];
    wvec[idx] = s;
}

__global__ __launch_bounds__(256)
void pack_sc(const float* __restrict__ pW_root, const float* __restrict__ pW_rel,
             float* __restrict__ wsc) {
    const int t = blockIdx.x * 256 + threadIdx.x;
    if (t < 256) wsc[t] = pW_root[t];
    else if (t < 512) wsc[t] = pW_rel[t - 256];
}

// ---------------------------------------------------------------------------
// Layer-1 dots+alpha straight from x: a_src[v,h] = x[v]. wvec_h  (wave/node)
// alpha[v] = {0.5*ain_h0, 0.5*asf_h0, 0.5*ain_h1, 0.5*asf_h1}
// ---------------------------------------------------------------------------
__global__ __launch_bounds__(256)
void dots_alpha_x(const float* __restrict__ x, const float* __restrict__ wvec,
                  float* __restrict__ alph) {
    const int v = blockIdx.x * 4 + (threadIdx.x >> 6);
    const int lane = threadIdx.x & 63;
    const int j = v & (NNODE - 1);

    const float4 xa = *reinterpret_cast<const float4*>(&x[(size_t)v * 512 + lane * 4]);
    const float4 xb = *reinterpret_cast<const float4*>(&x[(size_t)v * 512 + 256 + lane * 4]);
    const float4 s0a = *reinterpret_cast<const float4*>(&wvec[0 * 512 + lane * 4]);
    const float4 s0b = *reinterpret_cast<const float4*>(&wvec[0 * 512 + 256 + lane * 4]);
    const float4 s1a = *reinterpret_cast<const float4*>(&wvec[1 * 512 + lane * 4]);
    const float4 s1b = *reinterpret_cast<const float4*>(&wvec[1 * 512 + 256 + lane * 4]);
    const float4 d0a = *reinterpret_cast<const float4*>(&wvec[2 * 512 + lane * 4]);
    const float4 d0b = *reinterpret_cast<const float4*>(&wvec[2 * 512 + 256 + lane * 4]);
    const float4 d1a = *reinterpret_cast<const float4*>(&wvec[3 * 512 + lane * 4]);
    const float4 d1b = *reinterpret_cast<const float4*>(&wvec[3 * 512 + 256 + lane * 4]);

    float sv0 = dot4(xa, s0a) + dot4(xb, s0b);
    float sv1 = dot4(xa, s1a) + dot4(xb, s1b);
    float dv0 = dot4(xa, d0a) + dot4(xb, d0b);
    float dv1 = dot4(xa, d1a) + dot4(xb, d1b);
    float sp0 = 0.f, sp1 = 0.f;
    if (j > 0) {
        const float4 pa = *reinterpret_cast<const float4*>(&x[(size_t)(v - 1) * 512 + lane * 4]);
        const float4 pb = *reinterpret_cast<const float4*>(&x[(size_t)(v - 1) * 512 + 256 + lane * 4]);
        sp0 = dot4(pa, s0a) + dot4(pb, s0b);
        sp1 = dot4(pa, s1a) + dot4(pb, s1b);
    }
#pragma unroll
    for (int off = 32; off; off >>= 1) {
        sv0 += __shfl_xor(sv0, off); sv1 += __shfl_xor(sv1, off);
        dv0 += __shfl_xor(dv0, off); dv1 += __shfl_xor(dv1, off);
        sp0 += __shfl_xor(sp0, off); sp1 += __shfl_xor(sp1, off);
    }
    if (lane == 0) {
        float4 o = {0.f, 0.5f, 0.f, 0.5f};
        if (j > 0) {
            {
                const float ein = leaky(sp0 + dv0), esf = leaky(sv0 + dv0);
                const float m = fmaxf(ein, esf);
                const float win = expf(ein - m), wsf = expf(esf - m);
                const float den = win + wsf + 1e-16f;
                o.x = 0.5f * win / den; o.y = 0.5f * wsf / den;
            }
            {
                const float ein = leaky(sp1 + dv1), esf = leaky(sv1 + dv1);
                const float m = fmaxf(ein, esf);
                const float win = expf(ein - m), wsf = expf(esf - m);
                const float den = win + wsf + 1e-16f;
                o.z = 0.5f * win / den; o.w = 0.5f * wsf / den;
            }
        }
        *reinterpret_cast<float4*>(&alph[(size_t)v * 4]) = o;
    }
}

// ---------------------------------------------------------------------------
// Layer-2 alpha from epilogue raw dots {s0,s1,d0,d1}
// ---------------------------------------------------------------------------
__global__ __launch_bounds__(256)
void alpha_from_dots(const float* __restrict__ rawd, float* __restrict__ alph) {
    const int v = blockIdx.x * 256 + threadIdx.x;
    if (v >= NT) return;
    const int j = v & (NNODE - 1);
    float4 o = {0.f, 0.5f, 0.f, 0.5f};
    if (j > 0) {
        const float4 dv = *reinterpret_cast<const float4*>(&rawd[(size_t)v * 4]);
        const float4 dp = *reinterpret_cast<const float4*>(&rawd[(size_t)(v - 1) * 4]);
        {
            const float ein = leaky(dp.x + dv.z), esf = leaky(dv.x + dv.z);
            const float m = fmaxf(ein, esf);
            const float win = expf(ein - m), wsf = expf(esf - m);
            const float den = win + wsf + 1e-16f;
            o.x = 0.5f * win / den; o.y = 0.5f * wsf / den;
        }
        {
            const float ein = leaky(dp.y + dv.w), esf = leaky(dv.y + dv.w);
            const float m = fmaxf(ein, esf);
            const float win = expf(ein - m), wsf = expf(esf - m);
            const float den = win + wsf + 1e-16f;
            o.z = 0.5f * win / den; o.w = 0.5f * wsf / den;
        }
    }
    *reinterpret_cast<float4*>(&alph[(size_t)v * 4]) = o;
}

// ---------------------------------------------------------------------------
// Per-graph top-K + gated mean pool + classifier.
// score[i] = rawsc[i].x + (i>0 ? rawsc[i-1].y : 0) + pb
// ---------------------------------------------------------------------------
__global__ __launch_bounds__(1024)
void topk_pool(const float* __restrict__ rawsc, const float* __restrict__ h,
               const float* __restrict__ cls_W, const float* __restrict__ cls_b,
               const float* __restrict__ pb, float* __restrict__ out) {
    __shared__ unsigned long long keys[NNODE];
    __shared__ float sc[NNODE];
    __shared__ float partial[4][256];
    __shared__ float red[8];

    const int b = blockIdx.x;
    const int tid = threadIdx.x;
    const float pbv = pb[0];

    for (int i = tid; i < NNODE; i += 1024) {
        float v = rawsc[((size_t)b * NNODE + i) * 2] + pbv;
        if (i > 0) v += rawsc[((size_t)b * NNODE + i - 1) * 2 + 1];
        sc[i] = v;
        unsigned u = __float_as_uint(v);
        u = (u & 0x80000000u) ? ~u : (u | 0x80000000u);
        keys[i] = ((unsigned long long)(~u) << 32) | (unsigned)i;
    }
    __syncthreads();

    for (int k = 2; k <= NNODE; k <<= 1) {
        for (int jj = k >> 1; jj > 0; jj >>= 1) {
            int i = ((tid & ~(jj - 1)) << 1) | (tid & (jj - 1));
            int ixj = i | jj;
            unsigned long long a = keys[i], c = keys[ixj];
            bool up = ((i & k) == 0);
            if ((a > c) == up) { keys[i] = c; keys[ixj] = a; }
            __syncthreads();
        }
    }

    const int g = tid >> 8;
    const int c = tid & 255;
    float acc = 0.f;
    for (int kk = g; kk < KKEEP; kk += 4) {
        int idx = (int)(keys[kk] & 0xffffffffu);
        float gate = tanhf(sc[idx]);
        acc += h[((size_t)b * NNODE + idx) * 256 + c] * gate;
    }
    partial[g][c] = acc;
    __syncthreads();

    if (tid < 256) {
        float pooled = (partial[0][tid] + partial[1][tid] +
                        partial[2][tid] + partial[3][tid]) / (float)KKEEP;
        float p0 = pooled * cls_W[tid * 2 + 0];
        float p1 = pooled * cls_W[tid * 2 + 1];
#pragma unroll
        for (int off = 32; off; off >>= 1) {
            p0 += __shfl_down(p0, off);
            p1 += __shfl_down(p1, off);
        }
        if ((tid & 63) == 0) {
            red[(tid >> 6) * 2 + 0] = p0;
            red[(tid >> 6) * 2 + 1] = p1;
        }
    }
    __syncthreads();
    if (tid == 0) {
        out[b * 2 + 0] = red[0] + red[2] + red[4] + red[6] + cls_b[0];
        out[b * 2 + 1] = red[1] + red[3] + red[5] + red[7] + cls_b[1];
    }
}

// ---------------------------------------------------------------------------

extern "C" void kernel_launch(void* const* d_in, const int* in_sizes, int n_in,
                              void* d_out, int out_size, void* d_ws, size_t ws_size,
                              hipStream_t stream) {
    const float* x        = (const float*)d_in[0];
    const float* W1       = (const float*)d_in[1];
    const float* att_src1 = (const float*)d_in[2];
    const float* att_dst1 = (const float*)d_in[3];
    const float* b1       = (const float*)d_in[4];
    const float* W2       = (const float*)d_in[5];
    const float* att_src2 = (const float*)d_in[6];
    const float* att_dst2 = (const float*)d_in[7];
    const float* b2       = (const float*)d_in[8];
    const float* pW_root  = (const float*)d_in[9];
    const float* pW_rel   = (const float*)d_in[10];
    const float* pb       = (const float*)d_in[11];
    const float* cls_W    = (const float*)d_in[12];
    const float* cls_b    = (const float*)d_in[13];
    float* out = (float*)d_out;

    // workspace (~277 MB):
    float* h1     = (float*)d_ws;               // NT*256 f32
    float* h2     = h1 + (size_t)NT * 256;      // NT*256 f32
    float* alpha1 = h2 + (size_t)NT * 256;      // NT*4
    float* rawd2  = alpha1 + (size_t)NT * 4;    // NT*4
    float* alpha2 = rawd2 + (size_t)NT * 4;     // NT*4
    float* rawsc  = alpha2 + (size_t)NT * 4;    // NT*2
    short* B1h    = (short*)(rawsc + (size_t)NT * 2);  // 256*1024
    short* B1l    = B1h + 256 * 1024;
    short* B2h    = B1l + 256 * 1024;           // 256*512
    short* B2l    = B2h + 256 * 512;
    float* wvec1  = (float*)(B2l + 256 * 512);  // 4*512
    float* wvec2  = wvec1 + 4 * 512;            // 4*256
    float* wsc    = wvec2 + 4 * 256;            // 512

    // ---- prep (tiny)
    build_wvec<<<(4 * 512 + 255) / 256, 256, 0, stream>>>(W1, att_src1, att_dst1, wvec1, 512);
    build_wvec<<<(4 * 256 + 255) / 256, 256, 0, stream>>>(W2, att_src2, att_dst2, wvec2, 256);
    build_B<<<(256 * 1024) / 256, 256, 0, stream>>>(W1, B1h, B1l, 512);
    build_B<<<(256 * 512) / 256, 256, 0, stream>>>(W2, B2h, B2l, 256);
    pack_sc<<<2, 256, 0, stream>>>(pW_root, pW_rel, wsc);

    // ---- layer 1: alphas from x, fused mix+GEMM -> h1 (+raw dots2)
    dots_alpha_x<<<NT / 4, 256, 0, stream>>>(x, wvec1, alpha1);
    gemm_fused<4, 1><<<NT / GBM, 512, 131072, stream>>>(
        x, B1h, B1l, alpha1, b1, wvec2, h1, rawd2, 1024);

    // ---- layer 2: alpha2 from raw dots, fused mix+GEMM -> h2 (+raw score pair)
    alpha_from_dots<<<NT / 256, 256, 0, stream>>>(rawd2, alpha2);
    gemm_fused<2, 0><<<NT / GBM, 512, 131072, stream>>>(
        h1, B2h, B2l, alpha2, b2, wsc, h2, rawsc, 512);

    // ---- SAGPool top-k + gated mean pool + classifier
    topk_pool<<<NGRAPH, 1024, 0, stream>>>(rawsc, h2, cls_W, cls_b, pb, out);
}